// Round 3
// baseline (3957.694 us; speedup 1.0000x reference)
//
#include <hip/hip_runtime.h>
#include <hip/hip_bf16.h>

// Problem: L=D=H=512 self-matching additive attention + bidirectional GRU.
// Inputs f32 (13 tensors), output f32 [512, 1024] = [hf | hb].
// Internal compute f32 in d_ws.

#define L 512
#define DD 512
#define HH 512

__device__ __forceinline__ float tanhf_fast(float x) {
    float ex = __expf(2.f * x);               // exp(2x); inf for large x is fine
    return 1.f - __fdividef(2.f, ex + 1.f);   // tanh(x); x->-inf => -1, x->+inf => 1
}

__device__ __forceinline__ float sigmoidf_fast(float x) {
    return __fdividef(1.f, 1.f + __expf(-x));
}

// ---------------- GEMM: C[M,N] = A[M,K] * op(B) + bias ----------------
// BT=1: B is [N,K] (use row n of B)  -> C = A @ B^T
// BT=0: B is [K,N]                    -> C = A @ B
template <int BT>
__global__ __launch_bounds__(256) void gemm_k(
    const float* __restrict__ A, const float* __restrict__ B,
    const float* __restrict__ bias, float* __restrict__ C,
    int M, int N, int K)
{
    __shared__ float As[16][68];
    __shared__ float Bs[16][68];
    int tid = threadIdx.x;
    int m0 = blockIdx.y * 64, n0 = blockIdx.x * 64;
    int tm = (tid & 15) * 4;
    int tn = (tid >> 4) * 4;
    float acc[4][4] = {};

    for (int k0 = 0; k0 < K; k0 += 16) {
        // A tile: 64 rows x 16 k
        {
            int c = tid & 15, r0 = tid >> 4;
#pragma unroll
            for (int q = 0; q < 4; q++) {
                int r = r0 + q * 16;
                As[c][r] = A[(size_t)(m0 + r) * K + k0 + c];
            }
        }
        if (BT) {
            int c = tid & 15, r0 = tid >> 4;
#pragma unroll
            for (int q = 0; q < 4; q++) {
                int n = r0 + q * 16;
                Bs[c][n] = B[(size_t)(n0 + n) * K + k0 + c];
            }
        } else {
            int n = tid & 63, r0 = tid >> 6;
#pragma unroll
            for (int q = 0; q < 4; q++) {
                int k = r0 + q * 4;
                Bs[k][n] = B[(size_t)(k0 + k) * N + n0 + n];
            }
        }
        __syncthreads();
#pragma unroll
        for (int k = 0; k < 16; k++) {
            float4 av = *(const float4*)&As[k][tm];
            float4 bv = *(const float4*)&Bs[k][tn];
            float a[4] = {av.x, av.y, av.z, av.w};
            float b[4] = {bv.x, bv.y, bv.z, bv.w};
#pragma unroll
            for (int i = 0; i < 4; i++)
#pragma unroll
                for (int j = 0; j < 4; j++) acc[i][j] += a[i] * b[j];
        }
        __syncthreads();
    }
#pragma unroll
    for (int i = 0; i < 4; i++) {
        float4 o;
        o.x = acc[i][0] + (bias ? bias[n0 + tn + 0] : 0.f);
        o.y = acc[i][1] + (bias ? bias[n0 + tn + 1] : 0.f);
        o.z = acc[i][2] + (bias ? bias[n0 + tn + 2] : 0.f);
        o.w = acc[i][3] + (bias ? bias[n0 + tn + 3] : 0.f);
        *(float4*)&C[(size_t)(m0 + tm + i) * N + n0 + tn] = o;
    }
}

// ---------------- attention scores e[t,j] = sum_d tanh(u[j,d]+w[t,d]) * v[j,d] ----
// block tile: 16 t x 32 j, loop d in chunks of 64. grid (16, 32).
__global__ __launch_bounds__(256) void attn_e_k(
    const float* __restrict__ u, const float* __restrict__ w,
    const float* __restrict__ v, float* __restrict__ e)
{
    __shared__ float wS[16][68];
    __shared__ float uS[32][68];
    __shared__ float vS[32][68];
    int tid = threadIdx.x;
    int t0 = blockIdx.y * 16, j0 = blockIdx.x * 32;
    int tt = tid >> 5, jj = tid & 31;
    float acc0 = 0.f, acc1 = 0.f;

    for (int d0 = 0; d0 < DD; d0 += 64) {
        {
            int c = tid & 63, r0 = tid >> 6;
#pragma unroll
            for (int q = 0; q < 4; q++)
                wS[r0 + q * 4][c] = w[(size_t)(t0 + r0 + q * 4) * DD + d0 + c];
#pragma unroll
            for (int q = 0; q < 8; q++) {
                int r = r0 + q * 4;
                uS[r][c] = u[(size_t)(j0 + r) * DD + d0 + c];
                vS[r][c] = v[(size_t)(j0 + r) * DD + d0 + c];
            }
        }
        __syncthreads();
#pragma unroll
        for (int c4 = 0; c4 < 16; c4++) {
            float4 uv = *(const float4*)&uS[jj][c4 * 4];
            float4 vv = *(const float4*)&vS[jj][c4 * 4];
            float4 w0 = *(const float4*)&wS[tt][c4 * 4];
            float4 w1 = *(const float4*)&wS[tt + 8][c4 * 4];
            acc0 += tanhf_fast(uv.x + w0.x) * vv.x;
            acc0 += tanhf_fast(uv.y + w0.y) * vv.y;
            acc0 += tanhf_fast(uv.z + w0.z) * vv.z;
            acc0 += tanhf_fast(uv.w + w0.w) * vv.w;
            acc1 += tanhf_fast(uv.x + w1.x) * vv.x;
            acc1 += tanhf_fast(uv.y + w1.y) * vv.y;
            acc1 += tanhf_fast(uv.z + w1.z) * vv.z;
            acc1 += tanhf_fast(uv.w + w1.w) * vv.w;
        }
        __syncthreads();
    }
    e[(size_t)(t0 + tt) * L + j0 + jj] = acc0;
    e[(size_t)(t0 + tt + 8) * L + j0 + jj] = acc1;
}

// ---------------- row softmax (in place), rows of length 512 ----------------
__global__ __launch_bounds__(256) void softmax_k(float* __restrict__ e) {
    int t = blockIdx.x;
    float* row = e + (size_t)t * L;
    int tid = threadIdx.x;
    float v0 = row[tid], v1 = row[tid + 256];
    float m = fmaxf(v0, v1);
#pragma unroll
    for (int off = 32; off > 0; off >>= 1) m = fmaxf(m, __shfl_xor(m, off));
    __shared__ float red[4];
    __shared__ float red2[4];
    int wid = tid >> 6, lane = tid & 63;
    if (lane == 0) red[wid] = m;
    __syncthreads();
    m = fmaxf(fmaxf(red[0], red[1]), fmaxf(red[2], red[3]));
    float e0 = __expf(v0 - m), e1 = __expf(v1 - m);
    float s = e0 + e1;
#pragma unroll
    for (int off = 32; off > 0; off >>= 1) s += __shfl_xor(s, off);
    if (lane == 0) red2[wid] = s;
    __syncthreads();
    s = red2[0] + red2[1] + red2[2] + red2[3];
    float inv = __fdividef(1.f, s);
    row[tid] = e0 * inv;
    row[tid + 256] = e1 * inv;
}

// ---------------- x = [v, c] ----------------
__global__ __launch_bounds__(256) void concat_k(
    const float* __restrict__ v, const float* __restrict__ c, float* __restrict__ x)
{
    int idx = blockIdx.x * 256 + threadIdx.x;  // 512*1024
    int t = idx >> 10, j = idx & 1023;
    x[idx] = (j < DD) ? v[(size_t)t * DD + j] : c[(size_t)t * DD + (j - DD)];
}

// ---------------- GRU scan, both directions ----------------
// 128 blocks x 256 threads. blocks [0,64): forward, [64,128): backward.
// Each block owns 8 h-indices (24 whh rows, held in registers: 64 f32/thread
// over 192 active threads). Per step: matvec from LDS h, gates, agent-scope
// h store DIRECTLY INTO d_out (fwd cols 0..511, bwd cols 512..1023, row
// stride 1024), monotonic-counter device barrier, reload h from d_out.
__global__ __launch_bounds__(256) void gru_scan_k(
    const float* __restrict__ whh_f, const float* __restrict__ bhh_f,
    const float* __restrict__ whh_b, const float* __restrict__ bhh_b,
    const float* __restrict__ gi_f, const float* __restrict__ gi_b,
    float* __restrict__ out,
    unsigned* __restrict__ cnt)
{
    int blk = blockIdx.x;
    int dir = blk >> 6;          // 0 fwd, 1 bwd
    int bi = blk & 63;
    int hbase = bi * 8;
    const float* whh = dir ? whh_b : whh_f;
    const float* bhh = dir ? bhh_b : bhh_f;
    const float* gi  = dir ? gi_b : gi_f;
    float* Hrow = out + dir * HH;     // row stride 1024
    unsigned* ctr = cnt + dir * 32;   // 128B apart

    __shared__ float hS[HH];
    __shared__ float ghS[24];

    int tid = threadIdx.x;
    int rr = tid >> 3, c8 = tid & 7;
    bool active = rr < 24;

    // stage this thread's 64 whh weights into registers
    float wreg[64];
    float bhv = 0.f;
    if (active) {
        int g = rr >> 3, i = rr & 7;
        const float* wrow = whh + ((size_t)(g * HH + hbase + i)) * HH + c8 * 64;
#pragma unroll
        for (int q = 0; q < 16; q++) {
            float4 wv = ((const float4*)wrow)[q];
            wreg[q * 4 + 0] = wv.x;
            wreg[q * 4 + 1] = wv.y;
            wreg[q * 4 + 2] = wv.z;
            wreg[q * 4 + 3] = wv.w;
        }
        if (c8 == 0) bhv = bhh[g * HH + hbase + i];
    }
    for (int j = tid; j < HH; j += 256) hS[j] = 0.f;
    __syncthreads();

    for (int s = 0; s < L; s++) {
        int t = dir ? (L - 1 - s) : s;

        // prefetch gi for the gate phase (independent of h)
        float ir = 0.f, iz = 0.f, inn = 0.f;
        if (tid < 8) {
            const float* git = gi + (size_t)t * (3 * HH);
            int hg = hbase + tid;
            ir  = git[hg];
            iz  = git[HH + hg];
            inn = git[2 * HH + hg];
        }

        float acc = 0.f;
        if (active) {
            const float4* h4 = (const float4*)(hS + c8 * 64);
#pragma unroll
            for (int q = 0; q < 16; q++) {
                float4 hv = h4[q];
                acc += wreg[q * 4 + 0] * hv.x;
                acc += wreg[q * 4 + 1] * hv.y;
                acc += wreg[q * 4 + 2] * hv.z;
                acc += wreg[q * 4 + 3] * hv.w;
            }
            acc += __shfl_xor(acc, 1);
            acc += __shfl_xor(acc, 2);
            acc += __shfl_xor(acc, 4);
            if (c8 == 0) ghS[rr] = acc + bhv;
        }
        __syncthreads();

        if (tid < 8) {
            int i = tid, hg = hbase + i;
            float r = sigmoidf_fast(ir + ghS[i]);
            float z = sigmoidf_fast(iz + ghS[8 + i]);
            float n = tanhf_fast(inn + r * ghS[16 + i]);
            float hnew = (1.f - z) * n + z * hS[hg];
            __hip_atomic_store(Hrow + (size_t)t * 1024 + hg, hnew,
                               __ATOMIC_RELAXED, __HIP_MEMORY_SCOPE_AGENT);
        }
        __syncthreads();  // all stores of this block drained (vmcnt 0 before barrier)

        if (tid == 0) {
            __threadfence();
            __hip_atomic_fetch_add(ctr, 1u, __ATOMIC_RELEASE, __HIP_MEMORY_SCOPE_AGENT);
            unsigned target = 64u * (unsigned)(s + 1);
            while (__hip_atomic_load(ctr, __ATOMIC_ACQUIRE, __HIP_MEMORY_SCOPE_AGENT) < target)
                __builtin_amdgcn_s_sleep(1);
        }
        __syncthreads();

        if (s < L - 1) {
            for (int j = tid; j < HH; j += 256)
                hS[j] = __hip_atomic_load(Hrow + (size_t)t * 1024 + j,
                                          __ATOMIC_RELAXED, __HIP_MEMORY_SCOPE_AGENT);
            __syncthreads();
        }
    }
}

extern "C" void kernel_launch(void* const* d_in, const int* in_sizes, int n_in,
                              void* d_out, int out_size, void* d_ws, size_t ws_size,
                              hipStream_t stream) {
    const float* v     = (const float*)d_in[0];
    const float* w1    = (const float*)d_in[1];
    const float* b1    = (const float*)d_in[2];
    const float* w2    = (const float*)d_in[3];
    const float* b2    = (const float*)d_in[4];
    const float* wih_f = (const float*)d_in[5];
    const float* whh_f = (const float*)d_in[6];
    const float* bih_f = (const float*)d_in[7];
    const float* bhh_f = (const float*)d_in[8];
    const float* wih_b = (const float*)d_in[9];
    const float* whh_b = (const float*)d_in[10];
    const float* bih_b = (const float*)d_in[11];
    const float* bhh_b = (const float*)d_in[12];
    float* out = (float*)d_out;   // f32 [512, 1024]

    float* ws = (float*)d_ws;
    float* u   = ws;                 // 512*512
    float* w_  = ws + 262144;        // 512*512
    float* e   = ws + 524288;        // 512*512 (becomes a after softmax)
    float* c   = ws + 786432;        // 512*512
    float* x   = ws + 1048576;       // 512*1024
    float* gif = ws + 1572864;       // 512*1536
    float* gib = ws + 2359296;       // 512*1536
    unsigned* cnt = (unsigned*)(ws + 3145728);

    // u = v @ w1^T + b1 ; w = v @ w2^T + b2
    gemm_k<1><<<dim3(8, 8), 256, 0, stream>>>(v, w1, b1, u, 512, 512, 512);
    gemm_k<1><<<dim3(8, 8), 256, 0, stream>>>(v, w2, b2, w_, 512, 512, 512);

    // e[t,j] = sum_d tanh(u[j,d]+w[t,d]) v[j,d]
    attn_e_k<<<dim3(16, 32), 256, 0, stream>>>(u, w_, v, e);
    softmax_k<<<512, 256, 0, stream>>>(e);

    // c = a @ v
    gemm_k<0><<<dim3(8, 8), 256, 0, stream>>>(e, v, nullptr, c, 512, 512, 512);

    // x = [v, c]
    concat_k<<<2048, 256, 0, stream>>>(v, c, x);

    // gi = x @ wih^T + bih (both directions)
    gemm_k<1><<<dim3(24, 8), 256, 0, stream>>>(x, wih_f, bih_f, gif, 512, 1536, 1024);
    gemm_k<1><<<dim3(24, 8), 256, 0, stream>>>(x, wih_b, bih_b, gib, 512, 1536, 1024);

    // barrier counters must start at 0 every launch (ws is re-poisoned to 0xAA)
    hipMemsetAsync(cnt, 0, 256, stream);

    gru_scan_k<<<128, 256, 0, stream>>>(whh_f, bhh_f, whh_b, bhh_b,
                                        gif, gib, out, cnt);
}

// Round 4
// 1996.216 us; speedup vs baseline: 1.9826x; 1.9826x over previous
//
#include <hip/hip_runtime.h>
#include <hip/hip_bf16.h>

// Problem: L=D=H=512 self-matching additive attention + bidirectional GRU.
// Inputs f32 (13 tensors), output f32 [512, 1024] = [hf | hb].
// Internal compute f32 in d_ws.

#define L 512
#define DD 512
#define HH 512

__device__ __forceinline__ float tanhf_fast(float x) {
    float ex = __expf(2.f * x);               // exp(2x); inf for large x is fine
    return 1.f - __fdividef(2.f, ex + 1.f);   // tanh(x); x->-inf => -1, x->+inf => 1
}

__device__ __forceinline__ float sigmoidf_fast(float x) {
    return __fdividef(1.f, 1.f + __expf(-x));
}

// ---------------- GEMM: C[M,N] = A[M,K] * op(B) + bias ----------------
// BT=1: B is [N,K] (use row n of B)  -> C = A @ B^T
// BT=0: B is [K,N]                    -> C = A @ B
template <int BT>
__global__ __launch_bounds__(256) void gemm_k(
    const float* __restrict__ A, const float* __restrict__ B,
    const float* __restrict__ bias, float* __restrict__ C,
    int M, int N, int K)
{
    __shared__ float As[16][68];
    __shared__ float Bs[16][68];
    int tid = threadIdx.x;
    int m0 = blockIdx.y * 64, n0 = blockIdx.x * 64;
    int tm = (tid & 15) * 4;
    int tn = (tid >> 4) * 4;
    float acc[4][4] = {};

    for (int k0 = 0; k0 < K; k0 += 16) {
        // A tile: 64 rows x 16 k
        {
            int c = tid & 15, r0 = tid >> 4;
#pragma unroll
            for (int q = 0; q < 4; q++) {
                int r = r0 + q * 16;
                As[c][r] = A[(size_t)(m0 + r) * K + k0 + c];
            }
        }
        if (BT) {
            int c = tid & 15, r0 = tid >> 4;
#pragma unroll
            for (int q = 0; q < 4; q++) {
                int n = r0 + q * 16;
                Bs[c][n] = B[(size_t)(n0 + n) * K + k0 + c];
            }
        } else {
            int n = tid & 63, r0 = tid >> 6;
#pragma unroll
            for (int q = 0; q < 4; q++) {
                int k = r0 + q * 4;
                Bs[k][n] = B[(size_t)(k0 + k) * N + n0 + n];
            }
        }
        __syncthreads();
#pragma unroll
        for (int k = 0; k < 16; k++) {
            float4 av = *(const float4*)&As[k][tm];
            float4 bv = *(const float4*)&Bs[k][tn];
            float a[4] = {av.x, av.y, av.z, av.w};
            float b[4] = {bv.x, bv.y, bv.z, bv.w};
#pragma unroll
            for (int i = 0; i < 4; i++)
#pragma unroll
                for (int j = 0; j < 4; j++) acc[i][j] += a[i] * b[j];
        }
        __syncthreads();
    }
#pragma unroll
    for (int i = 0; i < 4; i++) {
        float4 o;
        o.x = acc[i][0] + (bias ? bias[n0 + tn + 0] : 0.f);
        o.y = acc[i][1] + (bias ? bias[n0 + tn + 1] : 0.f);
        o.z = acc[i][2] + (bias ? bias[n0 + tn + 2] : 0.f);
        o.w = acc[i][3] + (bias ? bias[n0 + tn + 3] : 0.f);
        *(float4*)&C[(size_t)(m0 + tm + i) * N + n0 + tn] = o;
    }
}

// ---------------- attention scores e[t,j] = sum_d tanh(u[j,d]+w[t,d]) * v[j,d] ----
// block tile: 16 t x 32 j, loop d in chunks of 64. grid (16, 32).
__global__ __launch_bounds__(256) void attn_e_k(
    const float* __restrict__ u, const float* __restrict__ w,
    const float* __restrict__ v, float* __restrict__ e)
{
    __shared__ float wS[16][68];
    __shared__ float uS[32][68];
    __shared__ float vS[32][68];
    int tid = threadIdx.x;
    int t0 = blockIdx.y * 16, j0 = blockIdx.x * 32;
    int tt = tid >> 5, jj = tid & 31;
    float acc0 = 0.f, acc1 = 0.f;

    for (int d0 = 0; d0 < DD; d0 += 64) {
        {
            int c = tid & 63, r0 = tid >> 6;
#pragma unroll
            for (int q = 0; q < 4; q++)
                wS[r0 + q * 4][c] = w[(size_t)(t0 + r0 + q * 4) * DD + d0 + c];
#pragma unroll
            for (int q = 0; q < 8; q++) {
                int r = r0 + q * 4;
                uS[r][c] = u[(size_t)(j0 + r) * DD + d0 + c];
                vS[r][c] = v[(size_t)(j0 + r) * DD + d0 + c];
            }
        }
        __syncthreads();
#pragma unroll
        for (int c4 = 0; c4 < 16; c4++) {
            float4 uv = *(const float4*)&uS[jj][c4 * 4];
            float4 vv = *(const float4*)&vS[jj][c4 * 4];
            float4 w0 = *(const float4*)&wS[tt][c4 * 4];
            float4 w1 = *(const float4*)&wS[tt + 8][c4 * 4];
            acc0 += tanhf_fast(uv.x + w0.x) * vv.x;
            acc0 += tanhf_fast(uv.y + w0.y) * vv.y;
            acc0 += tanhf_fast(uv.z + w0.z) * vv.z;
            acc0 += tanhf_fast(uv.w + w0.w) * vv.w;
            acc1 += tanhf_fast(uv.x + w1.x) * vv.x;
            acc1 += tanhf_fast(uv.y + w1.y) * vv.y;
            acc1 += tanhf_fast(uv.z + w1.z) * vv.z;
            acc1 += tanhf_fast(uv.w + w1.w) * vv.w;
        }
        __syncthreads();
    }
    e[(size_t)(t0 + tt) * L + j0 + jj] = acc0;
    e[(size_t)(t0 + tt + 8) * L + j0 + jj] = acc1;
}

// ---------------- row softmax (in place), rows of length 512 ----------------
__global__ __launch_bounds__(256) void softmax_k(float* __restrict__ e) {
    int t = blockIdx.x;
    float* row = e + (size_t)t * L;
    int tid = threadIdx.x;
    float v0 = row[tid], v1 = row[tid + 256];
    float m = fmaxf(v0, v1);
#pragma unroll
    for (int off = 32; off > 0; off >>= 1) m = fmaxf(m, __shfl_xor(m, off));
    __shared__ float red[4];
    __shared__ float red2[4];
    int wid = tid >> 6, lane = tid & 63;
    if (lane == 0) red[wid] = m;
    __syncthreads();
    m = fmaxf(fmaxf(red[0], red[1]), fmaxf(red[2], red[3]));
    float e0 = __expf(v0 - m), e1 = __expf(v1 - m);
    float s = e0 + e1;
#pragma unroll
    for (int off = 32; off > 0; off >>= 1) s += __shfl_xor(s, off);
    if (lane == 0) red2[wid] = s;
    __syncthreads();
    s = red2[0] + red2[1] + red2[2] + red2[3];
    float inv = __fdividef(1.f, s);
    row[tid] = e0 * inv;
    row[tid + 256] = e1 * inv;
}

// ---------------- x = [v, c] ----------------
__global__ __launch_bounds__(256) void concat_k(
    const float* __restrict__ v, const float* __restrict__ c, float* __restrict__ x)
{
    int idx = blockIdx.x * 256 + threadIdx.x;  // 512*1024
    int t = idx >> 10, j = idx & 1023;
    x[idx] = (j < DD) ? v[(size_t)t * DD + j] : c[(size_t)t * DD + (j - DD)];
}

// ---------------- GRU scan, both directions ----------------
// 128 blocks x 256 threads. blocks [0,64): forward, [64,128): backward.
// Each block owns 8 h-indices (24 whh rows in registers, interleaved column
// layout so the LDS matvec reads are bank-conflict-free).
// Per step: matvec from LDS h, gates, RELAXED agent-scope store of hnew to a
// ping-pong L3 staging buffer (+ plain store to out), __syncthreads (drains
// vmcnt => stores visible at coherence point), per-block flag store, wave-0
// polls all 64 flags with one coalesced load, reload h. No fences, no RMW,
// no acquire => no per-step cache-maintenance ops.
__global__ __launch_bounds__(256) void gru_scan_k(
    const float* __restrict__ whh_f, const float* __restrict__ bhh_f,
    const float* __restrict__ whh_b, const float* __restrict__ bhh_b,
    const float* __restrict__ gi_f, const float* __restrict__ gi_b,
    float* __restrict__ out,
    float* __restrict__ hstage,      // [2 dirs][2 parity][512]
    unsigned* __restrict__ flags)    // [2 dirs][64]
{
    int blk = blockIdx.x;
    int dir = blk >> 6;          // 0 fwd, 1 bwd
    int bi = blk & 63;
    int hbase = bi * 8;
    const float* whh = dir ? whh_b : whh_f;
    const float* bhh = dir ? bhh_b : bhh_f;
    const float* gi  = dir ? gi_b : gi_f;
    float* outBase = out + dir * HH;       // row stride 1024
    float* stage = hstage + dir * 1024;
    unsigned* flg = flags + dir * 64;

    __shared__ float hS[HH];
    __shared__ float ghS[24];

    int tid = threadIdx.x;
    int rr = tid >> 3, c8 = tid & 7;
    bool active = rr < 24;

    // stage this thread's whh weights into registers, interleaved columns:
    // thread c8 owns float4 slots {q*8 + c8 : q in [0,16)} of its row.
    float4 wreg[16];
    float bhv = 0.f;
    if (active) {
        int g = rr >> 3, i = rr & 7;
        const float4* wrow = (const float4*)(whh + (size_t)(g * HH + hbase + i) * HH);
#pragma unroll
        for (int q = 0; q < 16; q++) wreg[q] = wrow[q * 8 + c8];
        if (c8 == 0) bhv = bhh[g * HH + hbase + i];
    }
    for (int j = tid; j < HH; j += 256) hS[j] = 0.f;

    // prefetch gi for step 0
    float ir = 0.f, iz = 0.f, inn = 0.f;
    if (tid < 8) {
        int t0 = dir ? (L - 1) : 0;
        const float* git = gi + (size_t)t0 * (3 * HH);
        ir  = git[hbase + tid];
        iz  = git[HH + hbase + tid];
        inn = git[2 * HH + hbase + tid];
    }
    __syncthreads();

    for (int s = 0; s < L; s++) {
        int t = dir ? (L - 1 - s) : s;

        float acc = 0.f;
        if (active) {
            const float4* h4 = (const float4*)hS;
#pragma unroll
            for (int q = 0; q < 16; q++) {
                float4 hv = h4[q * 8 + c8];   // lanes' addrs 16B apart: all 32 banks
                acc += wreg[q].x * hv.x + wreg[q].y * hv.y
                     + wreg[q].z * hv.z + wreg[q].w * hv.w;
            }
            acc += __shfl_xor(acc, 1);
            acc += __shfl_xor(acc, 2);
            acc += __shfl_xor(acc, 4);
            if (c8 == 0) ghS[rr] = acc + bhv;
        }
        __syncthreads();

        if (tid < 8) {
            int i = tid, hg = hbase + i;
            float r = sigmoidf_fast(ir + ghS[i]);
            float z = sigmoidf_fast(iz + ghS[8 + i]);
            float n = tanhf_fast(inn + r * ghS[16 + i]);
            float hnew = (1.f - z) * n + z * hS[hg];
            outBase[(size_t)t * 1024 + hg] = hnew;     // final output, off critical path
            __hip_atomic_store(stage + (s & 1) * 512 + hg, hnew,
                               __ATOMIC_RELAXED, __HIP_MEMORY_SCOPE_AGENT);
        }
        __syncthreads();   // vmcnt(0) drained: staging stores visible at L3

        if (s == L - 1) break;

        if (tid == 0)
            __hip_atomic_store(flg + bi, (unsigned)(s + 1),
                               __ATOMIC_RELAXED, __HIP_MEMORY_SCOPE_AGENT);

        // prefetch next step's gi while we wait on the barrier
        if (tid < 8) {
            int tn = dir ? (L - 2 - s) : (s + 1);
            const float* git = gi + (size_t)tn * (3 * HH);
            ir  = git[hbase + tid];
            iz  = git[HH + hbase + tid];
            inn = git[2 * HH + hbase + tid];
        }

        if (tid < 64) {
            unsigned target = (unsigned)(s + 1);
            while (true) {
                unsigned f = __hip_atomic_load(flg + tid, __ATOMIC_RELAXED,
                                               __HIP_MEMORY_SCOPE_AGENT);
                if (__all(f >= target)) break;
            }
        }
        __syncthreads();

        // reload h (ping-pong buffer written this step; overwrite-safety:
        // a block can only reach parity reuse after ALL blocks passed the
        // next barrier, which is after their reload completed)
        {
            const float* src = stage + (s & 1) * 512;
            hS[tid]       = __hip_atomic_load(src + tid, __ATOMIC_RELAXED,
                                              __HIP_MEMORY_SCOPE_AGENT);
            hS[tid + 256] = __hip_atomic_load(src + tid + 256, __ATOMIC_RELAXED,
                                              __HIP_MEMORY_SCOPE_AGENT);
        }
        __syncthreads();
    }
}

extern "C" void kernel_launch(void* const* d_in, const int* in_sizes, int n_in,
                              void* d_out, int out_size, void* d_ws, size_t ws_size,
                              hipStream_t stream) {
    const float* v     = (const float*)d_in[0];
    const float* w1    = (const float*)d_in[1];
    const float* b1    = (const float*)d_in[2];
    const float* w2    = (const float*)d_in[3];
    const float* b2    = (const float*)d_in[4];
    const float* wih_f = (const float*)d_in[5];
    const float* whh_f = (const float*)d_in[6];
    const float* bih_f = (const float*)d_in[7];
    const float* bhh_f = (const float*)d_in[8];
    const float* wih_b = (const float*)d_in[9];
    const float* whh_b = (const float*)d_in[10];
    const float* bih_b = (const float*)d_in[11];
    const float* bhh_b = (const float*)d_in[12];
    float* out = (float*)d_out;   // f32 [512, 1024]

    float* ws = (float*)d_ws;
    float* u   = ws;                 // 512*512
    float* w_  = ws + 262144;        // 512*512
    float* e   = ws + 524288;        // 512*512 (becomes a after softmax)
    float* c   = ws + 786432;        // 512*512
    float* x   = ws + 1048576;       // 512*1024
    float* gif = ws + 1572864;       // 512*1536
    float* gib = ws + 2359296;       // 512*1536
    float* hstage = ws + 3145728;    // 2*2*512
    unsigned* flags = (unsigned*)(ws + 3145728 + 2048);  // 2*64 u32

    // u = v @ w1^T + b1 ; w = v @ w2^T + b2
    gemm_k<1><<<dim3(8, 8), 256, 0, stream>>>(v, w1, b1, u, 512, 512, 512);
    gemm_k<1><<<dim3(8, 8), 256, 0, stream>>>(v, w2, b2, w_, 512, 512, 512);

    // e[t,j] = sum_d tanh(u[j,d]+w[t,d]) v[j,d]
    attn_e_k<<<dim3(16, 32), 256, 0, stream>>>(u, w_, v, e);
    softmax_k<<<512, 256, 0, stream>>>(e);

    // c = a @ v
    gemm_k<0><<<dim3(8, 8), 256, 0, stream>>>(e, v, nullptr, c, 512, 512, 512);

    // x = [v, c]
    concat_k<<<2048, 256, 0, stream>>>(v, c, x);

    // gi = x @ wih^T + bih (both directions)
    gemm_k<1><<<dim3(24, 8), 256, 0, stream>>>(x, wih_f, bih_f, gif, 512, 1536, 1024);
    gemm_k<1><<<dim3(24, 8), 256, 0, stream>>>(x, wih_b, bih_b, gib, 512, 1536, 1024);

    // flags must start at 0 every launch (ws is re-poisoned to 0xAA)
    hipMemsetAsync(flags, 0, 512, stream);

    gru_scan_k<<<128, 256, 0, stream>>>(whh_f, bhh_f, whh_b, bhh_b,
                                        gif, gib, out, hstage, flags);
}

// Round 6
// 1343.305 us; speedup vs baseline: 2.9462x; 1.4860x over previous
//
#include <hip/hip_runtime.h>
#include <hip/hip_bf16.h>

// Problem: L=D=H=512 self-matching additive attention + bidirectional GRU.
// Inputs f32 (13 tensors), output f32 [512, 1024] = [hf | hb].
// Internal compute f32 in d_ws.

#define L 512
#define DD 512
#define HH 512

__device__ __forceinline__ float tanhf_fast(float x) {
    float ex = __expf(2.f * x);               // exp(2x); inf for large x is fine
    return 1.f - __fdividef(2.f, ex + 1.f);   // tanh(x); x->-inf => -1, x->+inf => 1
}

__device__ __forceinline__ float sigmoidf_fast(float x) {
    return __fdividef(1.f, 1.f + __expf(-x));
}

// ---------------- GEMM: C[M,N] = A[M,K] * op(B) + bias ----------------
// BT=1: B is [N,K] (use row n of B)  -> C = A @ B^T
// BT=0: B is [K,N]                    -> C = A @ B
template <int BT>
__global__ __launch_bounds__(256) void gemm_k(
    const float* __restrict__ A, const float* __restrict__ B,
    const float* __restrict__ bias, float* __restrict__ C,
    int M, int N, int K)
{
    __shared__ float As[16][68];
    __shared__ float Bs[16][68];
    int tid = threadIdx.x;
    int m0 = blockIdx.y * 64, n0 = blockIdx.x * 64;
    int tm = (tid & 15) * 4;
    int tn = (tid >> 4) * 4;
    float acc[4][4] = {};

    for (int k0 = 0; k0 < K; k0 += 16) {
        // A tile: 64 rows x 16 k
        {
            int c = tid & 15, r0 = tid >> 4;
#pragma unroll
            for (int q = 0; q < 4; q++) {
                int r = r0 + q * 16;
                As[c][r] = A[(size_t)(m0 + r) * K + k0 + c];
            }
        }
        if (BT) {
            int c = tid & 15, r0 = tid >> 4;
#pragma unroll
            for (int q = 0; q < 4; q++) {
                int n = r0 + q * 16;
                Bs[c][n] = B[(size_t)(n0 + n) * K + k0 + c];
            }
        } else {
            int n = tid & 63, r0 = tid >> 6;
#pragma unroll
            for (int q = 0; q < 4; q++) {
                int k = r0 + q * 4;
                Bs[k][n] = B[(size_t)(k0 + k) * N + n0 + n];
            }
        }
        __syncthreads();
#pragma unroll
        for (int k = 0; k < 16; k++) {
            float4 av = *(const float4*)&As[k][tm];
            float4 bv = *(const float4*)&Bs[k][tn];
            float a[4] = {av.x, av.y, av.z, av.w};
            float b[4] = {bv.x, bv.y, bv.z, bv.w};
#pragma unroll
            for (int i = 0; i < 4; i++)
#pragma unroll
                for (int j = 0; j < 4; j++) acc[i][j] += a[i] * b[j];
        }
        __syncthreads();
    }
#pragma unroll
    for (int i = 0; i < 4; i++) {
        float4 o;
        o.x = acc[i][0] + (bias ? bias[n0 + tn + 0] : 0.f);
        o.y = acc[i][1] + (bias ? bias[n0 + tn + 1] : 0.f);
        o.z = acc[i][2] + (bias ? bias[n0 + tn + 2] : 0.f);
        o.w = acc[i][3] + (bias ? bias[n0 + tn + 3] : 0.f);
        *(float4*)&C[(size_t)(m0 + tm + i) * N + n0 + tn] = o;
    }
}

// ---------------- attention scores e[t,j] = sum_d tanh(u[j,d]+w[t,d]) * v[j,d] ----
// block tile: 16 t x 32 j, loop d in chunks of 64. grid (16, 32).
__global__ __launch_bounds__(256) void attn_e_k(
    const float* __restrict__ u, const float* __restrict__ w,
    const float* __restrict__ v, float* __restrict__ e)
{
    __shared__ float wS[16][68];
    __shared__ float uS[32][68];
    __shared__ float vS[32][68];
    int tid = threadIdx.x;
    int t0 = blockIdx.y * 16, j0 = blockIdx.x * 32;
    int tt = tid >> 5, jj = tid & 31;
    float acc0 = 0.f, acc1 = 0.f;

    for (int d0 = 0; d0 < DD; d0 += 64) {
        {
            int c = tid & 63, r0 = tid >> 6;
#pragma unroll
            for (int q = 0; q < 4; q++)
                wS[r0 + q * 4][c] = w[(size_t)(t0 + r0 + q * 4) * DD + d0 + c];
#pragma unroll
            for (int q = 0; q < 8; q++) {
                int r = r0 + q * 4;
                uS[r][c] = u[(size_t)(j0 + r) * DD + d0 + c];
                vS[r][c] = v[(size_t)(j0 + r) * DD + d0 + c];
            }
        }
        __syncthreads();
#pragma unroll
        for (int c4 = 0; c4 < 16; c4++) {
            float4 uv = *(const float4*)&uS[jj][c4 * 4];
            float4 vv = *(const float4*)&vS[jj][c4 * 4];
            float4 w0 = *(const float4*)&wS[tt][c4 * 4];
            float4 w1 = *(const float4*)&wS[tt + 8][c4 * 4];
            acc0 += tanhf_fast(uv.x + w0.x) * vv.x;
            acc0 += tanhf_fast(uv.y + w0.y) * vv.y;
            acc0 += tanhf_fast(uv.z + w0.z) * vv.z;
            acc0 += tanhf_fast(uv.w + w0.w) * vv.w;
            acc1 += tanhf_fast(uv.x + w1.x) * vv.x;
            acc1 += tanhf_fast(uv.y + w1.y) * vv.y;
            acc1 += tanhf_fast(uv.z + w1.z) * vv.z;
            acc1 += tanhf_fast(uv.w + w1.w) * vv.w;
        }
        __syncthreads();
    }
    e[(size_t)(t0 + tt) * L + j0 + jj] = acc0;
    e[(size_t)(t0 + tt + 8) * L + j0 + jj] = acc1;
}

// ---------------- row softmax (in place), rows of length 512 ----------------
__global__ __launch_bounds__(256) void softmax_k(float* __restrict__ e) {
    int t = blockIdx.x;
    float* row = e + (size_t)t * L;
    int tid = threadIdx.x;
    float v0 = row[tid], v1 = row[tid + 256];
    float m = fmaxf(v0, v1);
#pragma unroll
    for (int off = 32; off > 0; off >>= 1) m = fmaxf(m, __shfl_xor(m, off));
    __shared__ float red[4];
    __shared__ float red2[4];
    int wid = tid >> 6, lane = tid & 63;
    if (lane == 0) red[wid] = m;
    __syncthreads();
    m = fmaxf(fmaxf(red[0], red[1]), fmaxf(red[2], red[3]));
    float e0 = __expf(v0 - m), e1 = __expf(v1 - m);
    float s = e0 + e1;
#pragma unroll
    for (int off = 32; off > 0; off >>= 1) s += __shfl_xor(s, off);
    if (lane == 0) red2[wid] = s;
    __syncthreads();
    s = red2[0] + red2[1] + red2[2] + red2[3];
    float inv = __fdividef(1.f, s);
    row[tid] = e0 * inv;
    row[tid + 256] = e1 * inv;
}

// ---------------- x = [v, c] ----------------
__global__ __launch_bounds__(256) void concat_k(
    const float* __restrict__ v, const float* __restrict__ c, float* __restrict__ x)
{
    int idx = blockIdx.x * 256 + threadIdx.x;  // 512*1024
    int t = idx >> 10, j = idx & 1023;
    x[idx] = (j < DD) ? v[(size_t)t * DD + j] : c[(size_t)t * DD + (j - DD)];
}

// ---------------- GRU scan, both directions ----------------
// 128 blocks x 256 threads. blocks [0,64): forward, [64,128): backward.
// Each block owns 8 h-indices (24 whh rows in registers, interleaved column
// layout => bank-conflict-free LDS matvec).
// h exchange: SELF-VALIDATING words. |h|<=1 (GRU invariant; tanh saturates to
// exactly +-1.0 which round-trips the encoding), so each value is encoded as
// 24-bit fixed point (scale 2^22) + 8-bit step tag in ONE u32.
// Producers store their 8 words (relaxed agent scope, no fence/drain needed);
// every thread polls exactly the 2 words it needs until the tag matches,
// decodes into LDS, __syncthreads. Ping-pong parity buffers; skew between
// blocks is bounded by 1 step, so 8-bit tags can never alias (and the 0xAA
// ws-poison tag never matches tags 1/2 of the first two polls => no memset).
__global__ __launch_bounds__(256) void gru_scan_k(
    const float* __restrict__ whh_f, const float* __restrict__ bhh_f,
    const float* __restrict__ whh_b, const float* __restrict__ bhh_b,
    const float* __restrict__ gi_f, const float* __restrict__ gi_b,
    float* __restrict__ out,
    unsigned* __restrict__ hstage)   // [2 dirs][2 parity][512] encoded u32
{
    int blk = blockIdx.x;
    int dir = blk >> 6;          // 0 fwd, 1 bwd
    int bi = blk & 63;
    int hbase = bi * 8;
    const float* whh = dir ? whh_b : whh_f;
    const float* bhh = dir ? bhh_b : bhh_f;
    const float* gi  = dir ? gi_b : gi_f;
    float* outBase = out + dir * HH;       // row stride 1024
    unsigned* stage = hstage + dir * 1024;

    __shared__ float hS[HH];
    __shared__ float ghS[24];

    int tid = threadIdx.x;
    int rr = tid >> 3, c8 = tid & 7;
    bool active = rr < 24;

    // whh weights into registers, interleaved columns: thread c8 owns float4
    // slots {q*8 + c8 : q in [0,16)} of its row (conflict-free LDS reads).
    float4 wreg[16];
    float bhv = 0.f;
    if (active) {
        int g = rr >> 3, i = rr & 7;
        const float4* wrow = (const float4*)(whh + (size_t)(g * HH + hbase + i) * HH);
#pragma unroll
        for (int q = 0; q < 16; q++) wreg[q] = wrow[q * 8 + c8];
        if (c8 == 0) bhv = bhh[g * HH + hbase + i];
    }
    for (int j = tid; j < HH; j += 256) hS[j] = 0.f;

    // prefetch gi for step 0
    float ir = 0.f, iz = 0.f, inn = 0.f;
    if (tid < 8) {
        int t0 = dir ? (L - 1) : 0;
        const float* git = gi + (size_t)t0 * (3 * HH);
        ir  = git[hbase + tid];
        iz  = git[HH + hbase + tid];
        inn = git[2 * HH + hbase + tid];
    }
    __syncthreads();

    const float ENC = 4194304.0f;            // 2^22
    const float DEC = 1.0f / 4194304.0f;

    for (int s = 0; s < L; s++) {
        int t = dir ? (L - 1 - s) : s;

        float acc = 0.f;
        if (active) {
            const float4* h4 = (const float4*)hS;
#pragma unroll
            for (int q = 0; q < 16; q++) {
                float4 hv = h4[q * 8 + c8];   // lanes 16B apart: all 32 banks
                acc += wreg[q].x * hv.x + wreg[q].y * hv.y
                     + wreg[q].z * hv.z + wreg[q].w * hv.w;
            }
            acc += __shfl_xor(acc, 1);
            acc += __shfl_xor(acc, 2);
            acc += __shfl_xor(acc, 4);
            if (c8 == 0) ghS[rr] = acc + bhv;
        }
        __syncthreads();

        if (tid < 8) {
            int i = tid, hg = hbase + i;
            float r = sigmoidf_fast(ir + ghS[i]);
            float z = sigmoidf_fast(iz + ghS[8 + i]);
            float n = tanhf_fast(inn + r * ghS[16 + i]);
            float hnew = (1.f - z) * n + z * hS[hg];
            outBase[(size_t)t * 1024 + hg] = hnew;   // full-precision output
            unsigned enc = ((unsigned)__float2int_rn(hnew * ENC) & 0x00FFFFFFu)
                         | ((unsigned)((s + 1) & 0xFF) << 24);
            __hip_atomic_store(stage + (s & 1) * 512 + hg, enc,
                               __ATOMIC_RELAXED, __HIP_MEMORY_SCOPE_AGENT);
        }

        if (s == L - 1) break;

        // prefetch next step's gi while waiting on data
        if (tid < 8) {
            int tn = dir ? (L - 2 - s) : (s + 1);
            const float* git = gi + (size_t)tn * (3 * HH);
            ir  = git[hbase + tid];
            iz  = git[HH + hbase + tid];
            inn = git[2 * HH + hbase + tid];
        }

        // poll the two words this thread consumes (data IS the flag)
        {
            unsigned tag = (unsigned)((s + 1) & 0xFF);
            const unsigned* src = stage + (s & 1) * 512;
            unsigned e0 = 0, e1 = 0;
            bool g0 = false, g1 = false;
            do {
                if (!g0) {
                    e0 = __hip_atomic_load(src + tid, __ATOMIC_RELAXED,
                                           __HIP_MEMORY_SCOPE_AGENT);
                    g0 = ((e0 >> 24) == tag);
                }
                if (!g1) {
                    e1 = __hip_atomic_load(src + tid + 256, __ATOMIC_RELAXED,
                                           __HIP_MEMORY_SCOPE_AGENT);
                    g1 = ((e1 >> 24) == tag);
                }
            } while (!(g0 && g1));
            hS[tid]       = (float)(((int)(e0 << 8)) >> 8) * DEC;
            hS[tid + 256] = (float)(((int)(e1 << 8)) >> 8) * DEC;
        }
        __syncthreads();
    }
}

extern "C" void kernel_launch(void* const* d_in, const int* in_sizes, int n_in,
                              void* d_out, int out_size, void* d_ws, size_t ws_size,
                              hipStream_t stream) {
    const float* v     = (const float*)d_in[0];
    const float* w1    = (const float*)d_in[1];
    const float* b1    = (const float*)d_in[2];
    const float* w2    = (const float*)d_in[3];
    const float* b2    = (const float*)d_in[4];
    const float* wih_f = (const float*)d_in[5];
    const float* whh_f = (const float*)d_in[6];
    const float* bih_f = (const float*)d_in[7];
    const float* bhh_f = (const float*)d_in[8];
    const float* wih_b = (const float*)d_in[9];
    const float* whh_b = (const float*)d_in[10];
    const float* bih_b = (const float*)d_in[11];
    const float* bhh_b = (const float*)d_in[12];
    float* out = (float*)d_out;   // f32 [512, 1024]

    float* ws = (float*)d_ws;
    float* u   = ws;                 // 512*512
    float* w_  = ws + 262144;        // 512*512
    float* e   = ws + 524288;        // 512*512 (becomes a after softmax)
    float* c   = ws + 786432;        // 512*512
    float* x   = ws + 1048576;       // 512*1024
    float* gif = ws + 1572864;       // 512*1536
    float* gib = ws + 2359296;       // 512*1536
    unsigned* hstage = (unsigned*)(ws + 3145728);  // 2*2*512 u32 (no init needed)

    // u = v @ w1^T + b1 ; w = v @ w2^T + b2
    gemm_k<1><<<dim3(8, 8), 256, 0, stream>>>(v, w1, b1, u, 512, 512, 512);
    gemm_k<1><<<dim3(8, 8), 256, 0, stream>>>(v, w2, b2, w_, 512, 512, 512);

    // e[t,j] = sum_d tanh(u[j,d]+w[t,d]) v[j,d]
    attn_e_k<<<dim3(16, 32), 256, 0, stream>>>(u, w_, v, e);
    softmax_k<<<512, 256, 0, stream>>>(e);

    // c = a @ v
    gemm_k<0><<<dim3(8, 8), 256, 0, stream>>>(e, v, nullptr, c, 512, 512, 512);

    // x = [v, c]
    concat_k<<<2048, 256, 0, stream>>>(v, c, x);

    // gi = x @ wih^T + bih (both directions)
    gemm_k<1><<<dim3(24, 8), 256, 0, stream>>>(x, wih_f, bih_f, gif, 512, 1536, 1024);
    gemm_k<1><<<dim3(24, 8), 256, 0, stream>>>(x, wih_b, bih_b, gib, 512, 1536, 1024);

    gru_scan_k<<<128, 256, 0, stream>>>(whh_f, bhh_f, whh_b, bhh_b,
                                        gif, gib, out, hstage);
}